// Round 5
// baseline (626.871 us; speedup 1.0000x reference)
//
#include <hip/hip_runtime.h>
#include <hip/hip_fp16.h>

// VectorQuantizer — round 5: mi=4 MFMA k_main (256 MFMA per 64 ds_read_b128),
// double-buffered global_load_lds B staging, register-only top-2 with single
// end merge, in-kernel exact-fp32 recheck of the block's own flagged pixels.
// k_epi reverted to fence-free r3 form (r4's __threadfence finalize regressed).
//
// score[k] = ||e_k||^2 - 2*dot(fp16(x),fp16(e_k)); ties (gap<TAU) exact-fp32.

#define C_DIM   256
#define K_CODES 1024
#define HW      4096
#define N_OUT   (16 * C_DIM * HW)
#define TAU     0.25f

typedef _Float16 f16x8 __attribute__((ext_vector_type(8)));
typedef float    f32x4 __attribute__((ext_vector_type(4)));
typedef unsigned u32x4 __attribute__((ext_vector_type(4)));

__device__ __forceinline__ void gld16(const void* g, void* lds) {
#if __has_builtin(__builtin_amdgcn_global_load_lds)
  __builtin_amdgcn_global_load_lds(
      (const __attribute__((address_space(1))) unsigned int*)g,
      (__attribute__((address_space(3))) unsigned int*)lds, 16, 0, 0);
#else
  ((int4*)lds)[threadIdx.x & 63] = *(const int4*)g;
#endif
}

// ---- fused prep: blocks 0-127 pack Bp; 128-383 e2; 384 zeros loss ---------
// Bp slot s: l=s&63, ks=(s>>6)&7, ni=(s>>9)&7, cb=s>>12
// code n = cb*128+ni*16+(l&15); c0 = ks*32+(l>>4)*8; 4 dw = 8 consecutive c
__global__ __launch_bounds__(256) void k_prep(const float* __restrict__ emb,
                                              float* __restrict__ e2,
                                              unsigned* __restrict__ Bp,
                                              float* __restrict__ lossp) {
  const int blk = blockIdx.x, t = threadIdx.x;
  if (blk < 128) {
    const int s = blk * 256 + t;
    const int l = s & 63, ks = (s >> 6) & 7, ni = (s >> 9) & 7, cb = s >> 12;
    const int n = (cb << 7) + (ni << 4) + (l & 15);
    const int c0 = (ks << 5) + ((l >> 4) << 3);
    const float* er = emb + (size_t)n * C_DIM + c0;
    u32x4 out;
#pragma unroll
    for (int d = 0; d < 4; ++d) {
      __half2 h = __floats2half2_rn(er[2 * d], er[2 * d + 1]);
      out[d] = *(unsigned*)&h;
    }
    *(u32x4*)(Bp + (size_t)s * 4) = out;
  } else if (blk < 384) {
    const int w = t >> 6, l = t & 63;
    const int k = (blk - 128) * 4 + w;
    const float4 v = *(const float4*)(emb + (size_t)k * C_DIM + l * 4);
    float s = v.x * v.x + v.y * v.y + v.z * v.z + v.w * v.w;
    for (int m = 32; m; m >>= 1) s += __shfl_down(s, m, 64);
    if (l == 0) e2[k] = s;
  } else if (t == 0) {
    *lossp = 0.f;
  }
}

// ---- main: 256 blocks x 256 px; wave = 64 px (mi=4), all 1024 codes -------
__global__ __launch_bounds__(256, 1) void k_main(
    const float* __restrict__ x, const unsigned* __restrict__ Bp,
    const float* __restrict__ e2g, const float* __restrict__ emb,
    int* __restrict__ idxw) {
  __shared__ unsigned Bs[2][16384];   // 2 x 64 KB double buffer
  __shared__ float e2s[K_CODES];      // 4 KB (exact fp32 — reused by recheck)
  __shared__ float xs[C_DIM];         // recheck pixel staging
  __shared__ int   flist[256];
  __shared__ int   fcnt;
  __shared__ float rd[4];
  __shared__ int   ri[4];

  const int t = threadIdx.x;
  const int wv = t >> 6, l = t & 63;
  const int l15 = l & 15, l4 = l >> 4;
  const int blk = blockIdx.x;         // 256 = 16 b * 16 stripes
  const int b = blk >> 4;
  const int p0 = (blk & 15) << 8;     // 256-px stripe
  const int pxw = p0 + (wv << 6);     // wave's 64-px base
  const float* xb = x + ((size_t)b << 20);

  if (t == 0) fcnt = 0;
#pragma unroll
  for (int i = 0; i < 4; ++i) e2s[t + 256 * i] = e2g[t + 256 * i];

  // stage pass 0 into buf 0 (16 gld16 per wave; wave-uniform LDS base)
#pragma unroll
  for (int i = 0; i < 16; ++i) {
    const int rbase = ((wv << 4) + i) << 8;           // dw
    gld16(Bp + rbase + (l << 2), (void*)&Bs[0][rbase]);
  }

  // A fragments: 4 mi x 8 ks, converted once, resident all kernel (128 VGPR)
  u32x4 afu[4][8];
#pragma unroll
  for (int mi = 0; mi < 4; ++mi) {
    const int px = pxw + (mi << 4) + l15;
#pragma unroll
    for (int ks = 0; ks < 8; ++ks) {
#pragma unroll
      for (int d = 0; d < 4; ++d) {
        const int c = (ks << 5) + (l4 << 3) + (d << 1);
        const float v0 = xb[((size_t)c << 12) + px];
        const float v1 = xb[((size_t)(c + 1) << 12) + px];
        __half2 h = __floats2half2_rn(v0, v1);
        afu[mi][ks][d] = *(unsigned*)&h;
      }
    }
  }
  __syncthreads();   // e2s + buf0 staged (barrier drains vmcnt)

  float d1[4][4], d2v[4][4];
  int   i1[4][4];
#pragma unroll
  for (int mi = 0; mi < 4; ++mi)
#pragma unroll
    for (int r = 0; r < 4; ++r) { d1[mi][r] = 1e30f; d2v[mi][r] = 1e30f; i1[mi][r] = 0; }

  for (int cb = 0; cb < 8; ++cb) {
    const int cur = cb & 1;
    if (cb < 7) {   // prefetch next pass into other buffer (lands by next barrier)
      const unsigned* src = Bp + ((size_t)(cb + 1) << 14);
#pragma unroll
      for (int i = 0; i < 16; ++i) {
        const int rbase = ((wv << 4) + i) << 8;
        gld16(src + rbase + (l << 2), (void*)&Bs[cur ^ 1][rbase]);
      }
    }

    f32x4 acc[4][8];
#pragma unroll
    for (int mi = 0; mi < 4; ++mi)
#pragma unroll
      for (int ni = 0; ni < 8; ++ni) acc[mi][ni] = (f32x4){0.f, 0.f, 0.f, 0.f};

#pragma unroll
    for (int ks = 0; ks < 8; ++ks) {
      const f16x8 a0 = __builtin_bit_cast(f16x8, afu[0][ks]);
      const f16x8 a1 = __builtin_bit_cast(f16x8, afu[1][ks]);
      const f16x8 a2 = __builtin_bit_cast(f16x8, afu[2][ks]);
      const f16x8 a3 = __builtin_bit_cast(f16x8, afu[3][ks]);
#pragma unroll
      for (int ni = 0; ni < 8; ++ni) {
        const f16x8 bf = __builtin_bit_cast(
            f16x8, *(const u32x4*)&Bs[cur][(((ni << 3) + ks) << 8) + (l << 2)]);
        acc[0][ni] = __builtin_amdgcn_mfma_f32_16x16x32_f16(a0, bf, acc[0][ni], 0, 0, 0);
        acc[1][ni] = __builtin_amdgcn_mfma_f32_16x16x32_f16(a1, bf, acc[1][ni], 0, 0, 0);
        acc[2][ni] = __builtin_amdgcn_mfma_f32_16x16x32_f16(a2, bf, acc[2][ni], 0, 0, 0);
        acc[3][ni] = __builtin_amdgcn_mfma_f32_16x16x32_f16(a3, bf, acc[3][ni], 0, 0, 0);
      }
    }

    // per-lane top-2 update — pure VALU
    const int cb128 = cb << 7;
#pragma unroll
    for (int ni = 0; ni < 8; ++ni) {
      const int   c   = cb128 + (ni << 4) + l15;
      const float e2v = e2s[c];
#pragma unroll
      for (int mi = 0; mi < 4; ++mi)
#pragma unroll
        for (int r = 0; r < 4; ++r) {
          const float s = fmaf(-2.f, acc[mi][ni][r], e2v);
          const bool lt = s < d1[mi][r];
          d2v[mi][r] = lt ? d1[mi][r] : (s < d2v[mi][r] ? s : d2v[mi][r]);
          i1[mi][r]  = lt ? c : i1[mi][r];
          d1[mi][r]  = lt ? s : d1[mi][r];
        }
    }
    __syncthreads();  // all waves done with Bs[cur]; prefetch for cb+1 drained
  }

  // single cross-lane merge (xor masks flip l15 bits — 16 lanes same pixel)
#pragma unroll
  for (int mi = 0; mi < 4; ++mi) {
#pragma unroll
    for (int r = 0; r < 4; ++r) {
      float pd1 = d1[mi][r], pd2 = d2v[mi][r];
      int   pi1 = i1[mi][r];
#pragma unroll
      for (int m = 1; m < 16; m <<= 1) {
        const float od1 = __shfl_xor(pd1, m);
        const float od2 = __shfl_xor(pd2, m);
        const int   oi1 = __shfl_xor(pi1, m);
        const bool take = (od1 < pd1) || (od1 == pd1 && oi1 < pi1);
        const float loser = take ? pd1 : od1;
        pd2 = fminf(fminf(pd2, od2), loser);
        pd1 = take ? od1 : pd1;
        pi1 = take ? oi1 : pi1;
      }
      if (l15 == 0) {
        const int px = pxw + (mi << 4) + (l4 << 2) + r;   // in-image pixel
        idxw[((size_t)b << 12) + px] = pi1;
        if (pd2 - pd1 < TAU) flist[atomicAdd(&fcnt, 1)] = px;  // cap 256 = block px
      }
    }
  }
  __syncthreads();

  // ---- in-block exact fp32 recheck of flagged pixels (r2-validated math) --
  const int n = fcnt;
  for (int ii = 0; ii < n; ++ii) {
    const int px = flist[ii];
    xs[t] = xb[((size_t)t << 12) + px];     // stage exact x[:,px]
    __syncthreads();
    const float* er = emb + (size_t)(t * 4) * C_DIM;
    float s0 = 0.f, s1 = 0.f, s2 = 0.f, s3 = 0.f;
    for (int c = 0; c < C_DIM; c += 4) {
      const float4 xv = *(const float4*)&xs[c];
      const float4 q0 = *(const float4*)(er + c);
      const float4 q1 = *(const float4*)(er + C_DIM + c);
      const float4 q2 = *(const float4*)(er + 2 * C_DIM + c);
      const float4 q3 = *(const float4*)(er + 3 * C_DIM + c);
      s0 = fmaf(q0.x, xv.x, s0); s0 = fmaf(q0.y, xv.y, s0);
      s0 = fmaf(q0.z, xv.z, s0); s0 = fmaf(q0.w, xv.w, s0);
      s1 = fmaf(q1.x, xv.x, s1); s1 = fmaf(q1.y, xv.y, s1);
      s1 = fmaf(q1.z, xv.z, s1); s1 = fmaf(q1.w, xv.w, s1);
      s2 = fmaf(q2.x, xv.x, s2); s2 = fmaf(q2.y, xv.y, s2);
      s2 = fmaf(q2.z, xv.z, s2); s2 = fmaf(q2.w, xv.w, s2);
      s3 = fmaf(q3.x, xv.x, s3); s3 = fmaf(q3.y, xv.y, s3);
      s3 = fmaf(q3.z, xv.z, s3); s3 = fmaf(q3.w, xv.w, s3);
    }
    float bd = e2s[4 * t] - 2.f * s0;
    int   bk = 4 * t;
    float dv;
    dv = e2s[4 * t + 1] - 2.f * s1; if (dv < bd) { bd = dv; bk = 4 * t + 1; }
    dv = e2s[4 * t + 2] - 2.f * s2; if (dv < bd) { bd = dv; bk = 4 * t + 2; }
    dv = e2s[4 * t + 3] - 2.f * s3; if (dv < bd) { bd = dv; bk = 4 * t + 3; }
#pragma unroll
    for (int m = 1; m < 64; m <<= 1) {
      const float od = __shfl_xor(bd, m);
      const int   oi = __shfl_xor(bk, m);
      if (od < bd || (od == bd && oi < bk)) { bd = od; bk = oi; }
    }
    if (l == 0) { rd[wv] = bd; ri[wv] = bk; }
    __syncthreads();
    if (t == 0) {
      for (int w2 = 1; w2 < 4; ++w2)
        if (rd[w2] < bd || (rd[w2] == bd && ri[w2] < bk)) { bd = rd[w2]; bk = ri[w2]; }
      idxw[((size_t)b << 12) + px] = bk;
    }
    __syncthreads();
  }
}

// ---- epilogue: gather + transposed store + loss (r3-validated, fence-free) -
__global__ __launch_bounds__(256) void k_epi(const float* __restrict__ x,
                                             const float* __restrict__ emb,
                                             const int* __restrict__ idxw,
                                             float* __restrict__ out,
                                             float* __restrict__ loss_acc) {
  __shared__ int bidx_s[64];
  __shared__ float lred[4];
  const int t = threadIdx.x;
  const int tile = blockIdx.x;     // 1024 = 16 b * 64
  const int b = tile >> 6, p0 = (tile & 63) << 6;
  const float* xb = x + ((size_t)b << 20) + p0;
  float* outb = out + ((size_t)b << 20) + p0;
  if (t < 64) bidx_s[t] = idxw[((size_t)b << 12) + p0 + t] & 1023;
  __syncthreads();
  float lsum = 0.f;
#pragma unroll 4
  for (int i = 0; i < 16; ++i) {
    const int fidx = t + 256 * i;
    const int c = fidx >> 4, p4 = (fidx & 15) << 2;
    const float4 x4 = *(const float4*)&xb[((size_t)c << 12) + p4];
    const int j0 = bidx_s[p4], j1 = bidx_s[p4 + 1], j2 = bidx_s[p4 + 2], j3 = bidx_s[p4 + 3];
    const float q0 = emb[(size_t)j0 * C_DIM + c];
    const float q1 = emb[(size_t)j1 * C_DIM + c];
    const float q2 = emb[(size_t)j2 * C_DIM + c];
    const float q3 = emb[(size_t)j3 * C_DIM + c];
    const float d0 = q0 - x4.x, dd1 = q1 - x4.y, dd2 = q2 - x4.z, dd3 = q3 - x4.w;
    lsum += d0 * d0 + dd1 * dd1 + dd2 * dd2 + dd3 * dd3;
    float4 o; o.x = q0; o.y = q1; o.z = q2; o.w = q3;
    *(float4*)&outb[((size_t)c << 12) + p4] = o;
  }
  for (int off = 32; off > 0; off >>= 1) lsum += __shfl_down(lsum, off, 64);
  if ((t & 63) == 0) lred[t >> 6] = lsum;
  __syncthreads();
  if (t == 0) atomicAdd(loss_acc, lred[0] + lred[1] + lred[2] + lred[3]);
}

__global__ void k_final(const float* __restrict__ ws, float* __restrict__ out) {
  out[N_OUT] = 2.0f * ws[0] / (float)N_OUT;
}

// ================= round-1 fp32 fallback (tiny ws) ==========================
__global__ void k_zero(float* ws) { ws[0] = 0.f; }

__global__ __launch_bounds__(256) void k_e2f(const float* __restrict__ emb,
                                             float* __restrict__ e2) {
  int k = blockIdx.x * 256 + threadIdx.x;
  const float* e = emb + (size_t)k * C_DIM;
  float s = 0.f;
#pragma unroll 8
  for (int c = 0; c < C_DIM; ++c) s += e[c] * e[c];
  e2[k] = s;
}

__global__ __launch_bounds__(256, 4) void k_main_r1(
    const float* __restrict__ x, const float* __restrict__ emb,
    const float* __restrict__ e2, float* __restrict__ out,
    float* __restrict__ loss_acc) {
  __shared__ float smem[64 * 64 + 64 * 64];
  float* xs = smem;
  float* es = smem + 64 * 64;
  float* red_d = smem;
  int* red_i = (int*)(smem + 64 * 16);
  int* bidx_s = (int*)(smem + 64 * 32);
  float* lred = smem + 64 * 32 + 64;
  const int t = threadIdx.x;
  const int tile = blockIdx.x;
  const int b = tile >> 6;
  const int p0 = (tile & 63) << 6;
  const float* xb = x + (size_t)b * C_DIM * HW + p0;
  const int pg = t & 15, kg = t >> 4;
  float best0 = 1e30f, best1 = 1e30f, best2 = 1e30f, best3 = 1e30f;
  int bi0 = 0, bi1 = 0, bi2 = 0, bi3 = 0;
  for (int kc = 0; kc < 16; ++kc) {
    const int k0 = kc * 64;
    float a00 = 0, a01 = 0, a02 = 0, a03 = 0, a10 = 0, a11 = 0, a12 = 0, a13 = 0;
    float a20 = 0, a21 = 0, a22 = 0, a23 = 0, a30 = 0, a31 = 0, a32 = 0, a33 = 0;
    for (int cs0 = 0; cs0 < 4; ++cs0) {
      __syncthreads();
#pragma unroll
      for (int i = 0; i < 4; ++i) {
        int fidx = t + 256 * i;
        int cs = fidx >> 4, p4 = (fidx & 15) << 2;
        *(float4*)&xs[cs * 64 + p4] = *(const float4*)&xb[(size_t)(cs0 * 64 + cs) * HW + p4];
      }
      for (int i = 0; i < 16; ++i) {
        int idx2 = t + 256 * i;
        int cs = idx2 >> 6, kk = idx2 & 63;
        es[cs * 64 + kk] = emb[(size_t)(k0 + kk) * C_DIM + cs0 * 64 + cs];
      }
      __syncthreads();
#pragma unroll 8
      for (int cs = 0; cs < 64; ++cs) {
        const float4 xv = *(const float4*)&xs[cs * 64 + (pg << 2)];
        const float4 ev = *(const float4*)&es[cs * 64 + (kg << 2)];
        a00 += xv.x * ev.x; a01 += xv.x * ev.y; a02 += xv.x * ev.z; a03 += xv.x * ev.w;
        a10 += xv.y * ev.x; a11 += xv.y * ev.y; a12 += xv.y * ev.z; a13 += xv.y * ev.w;
        a20 += xv.z * ev.x; a21 += xv.z * ev.y; a22 += xv.z * ev.z; a23 += xv.z * ev.w;
        a30 += xv.w * ev.x; a31 += xv.w * ev.y; a32 += xv.w * ev.z; a33 += xv.w * ev.w;
      }
    }
    const int kb = k0 + (kg << 2);
    const float e20 = e2[kb], e21 = e2[kb + 1], e22 = e2[kb + 2], e23 = e2[kb + 3];
    float s;
    s = e20 - 2.f * a00; if (s < best0) { best0 = s; bi0 = kb; }
    s = e21 - 2.f * a01; if (s < best0) { best0 = s; bi0 = kb + 1; }
    s = e22 - 2.f * a02; if (s < best0) { best0 = s; bi0 = kb + 2; }
    s = e23 - 2.f * a03; if (s < best0) { best0 = s; bi0 = kb + 3; }
    s = e20 - 2.f * a10; if (s < best1) { best1 = s; bi1 = kb; }
    s = e21 - 2.f * a11; if (s < best1) { best1 = s; bi1 = kb + 1; }
    s = e22 - 2.f * a12; if (s < best1) { best1 = s; bi1 = kb + 2; }
    s = e23 - 2.f * a13; if (s < best1) { best1 = s; bi1 = kb + 3; }
    s = e20 - 2.f * a20; if (s < best2) { best2 = s; bi2 = kb; }
    s = e21 - 2.f * a21; if (s < best2) { best2 = s; bi2 = kb + 1; }
    s = e22 - 2.f * a22; if (s < best2) { best2 = s; bi2 = kb + 2; }
    s = e23 - 2.f * a23; if (s < best2) { best2 = s; bi2 = kb + 3; }
    s = e20 - 2.f * a30; if (s < best3) { best3 = s; bi3 = kb; }
    s = e21 - 2.f * a31; if (s < best3) { best3 = s; bi3 = kb + 1; }
    s = e22 - 2.f * a32; if (s < best3) { best3 = s; bi3 = kb + 2; }
    s = e23 - 2.f * a33; if (s < best3) { best3 = s; bi3 = kb + 3; }
  }
  __syncthreads();
  const int prow = pg << 2;
  red_d[(prow + 0) * 16 + kg] = best0; red_i[(prow + 0) * 16 + kg] = bi0;
  red_d[(prow + 1) * 16 + kg] = best1; red_i[(prow + 1) * 16 + kg] = bi1;
  red_d[(prow + 2) * 16 + kg] = best2; red_i[(prow + 2) * 16 + kg] = bi2;
  red_d[(prow + 3) * 16 + kg] = best3; red_i[(prow + 3) * 16 + kg] = bi3;
  __syncthreads();
  if (t < 64) {
    float bd = red_d[t * 16];
    int bk = red_i[t * 16];
    for (int g = 1; g < 16; ++g) {
      float d = red_d[t * 16 + g];
      int k = red_i[t * 16 + g];
      if (d < bd || (d == bd && k < bk)) { bd = d; bk = k; }
    }
    bidx_s[t] = bk;
  }
  __syncthreads();
  float lsum = 0.f;
  float* outb = out + (size_t)b * C_DIM * HW + p0;
#pragma unroll 4
  for (int i = 0; i < 16; ++i) {
    int fidx = t + 256 * i;
    int c = fidx >> 4, p4 = (fidx & 15) << 2;
    const float4 x4 = *(const float4*)&xb[(size_t)c * HW + p4];
    const int j0 = bidx_s[p4], j1 = bidx_s[p4 + 1], j2 = bidx_s[p4 + 2], j3 = bidx_s[p4 + 3];
    const float q0 = emb[(size_t)j0 * C_DIM + c];
    const float q1 = emb[(size_t)j1 * C_DIM + c];
    const float q2 = emb[(size_t)j2 * C_DIM + c];
    const float q3 = emb[(size_t)j3 * C_DIM + c];
    const float d0 = q0 - x4.x, d1 = q1 - x4.y, d2 = q2 - x4.z, d3 = q3 - x4.w;
    lsum += d0 * d0 + d1 * d1 + d2 * d2 + d3 * d3;
    float4 o; o.x = q0; o.y = q1; o.z = q2; o.w = q3;
    *(float4*)&outb[(size_t)c * HW + p4] = o;
  }
  for (int off = 32; off > 0; off >>= 1) lsum += __shfl_down(lsum, off, 64);
  if ((t & 63) == 0) lred[t >> 6] = lsum;
  __syncthreads();
  if (t == 0) atomicAdd(loss_acc, lred[0] + lred[1] + lred[2] + lred[3]);
}

// ============================================================================
extern "C" void kernel_launch(void* const* d_in, const int* in_sizes, int n_in,
                              void* d_out, int out_size, void* d_ws, size_t ws_size,
                              hipStream_t stream) {
  const float* x = (const float*)d_in[0];
  const float* emb = (const float*)d_in[1];
  float* out = (float*)d_out;
  char* ws = (char*)d_ws;

  // ws: 0 loss | 256 e2 (4 KB) | 8192 idx (256 KB) | 335872 Bp (512 KB)
  const size_t NEED = 860160;
  if (ws_size >= NEED) {
    float* lossp = (float*)ws;
    float* e2 = (float*)(ws + 256);
    int* idx = (int*)(ws + 8192);
    unsigned* Bp = (unsigned*)(ws + 335872);
    k_prep<<<385, 256, 0, stream>>>(emb, e2, Bp, lossp);
    k_main<<<256, 256, 0, stream>>>(x, Bp, e2, emb, idx);
    k_epi<<<1024, 256, 0, stream>>>(x, emb, idx, out, lossp);
    k_final<<<1, 1, 0, stream>>>(lossp, out);
  } else {
    float* wsf = (float*)ws;
    float* e2 = wsf + 64;
    k_zero<<<1, 1, 0, stream>>>(wsf);
    k_e2f<<<K_CODES / 256, 256, 0, stream>>>(emb, e2);
    k_main_r1<<<1024, 256, 0, stream>>>(x, emb, e2, out, wsf);
    k_final<<<1, 1, 0, stream>>>(wsf, out);
  }
}

// Round 6
// 586.111 us; speedup vs baseline: 1.0695x; 1.0695x over previous
//
#include <hip/hip_runtime.h>
#include <hip/hip_fp16.h>

// VectorQuantizer — round 6: single fused main kernel.
//   * r3 occupancy shape: 512 blocks x 4 waves, mi=2 (32 px/wave), 2 blocks/CU
//   * 64-code passes, double-buffered gld16 B staging (prefetch hides L2 lat)
//   * register-only top-2, one cross-lane merge at end (no per-pass DS merges)
//   * in-block exact-fp32 recheck of near-ties (gap < TAU) [r5-validated]
//   * fused epilogue: gather + transposed store + loss on own 128-px stripe
// 3 dispatches: k_prep, k_main, k_final.
//
// score[k] = ||e_k||^2 - 2*dot(fp16(x),fp16(e_k))  [fp32 MFMA accum]

#define C_DIM   256
#define K_CODES 1024
#define HW      4096
#define N_OUT   (16 * C_DIM * HW)
#define TAU     0.25f

typedef _Float16 f16x8 __attribute__((ext_vector_type(8)));
typedef float    f32x4 __attribute__((ext_vector_type(4)));
typedef unsigned u32x4 __attribute__((ext_vector_type(4)));

__device__ __forceinline__ void gld16(const void* g, void* lds) {
#if __has_builtin(__builtin_amdgcn_global_load_lds)
  __builtin_amdgcn_global_load_lds(
      (const __attribute__((address_space(1))) unsigned int*)g,
      (__attribute__((address_space(3))) unsigned int*)lds, 16, 0, 0);
#else
  ((int4*)lds)[threadIdx.x & 63] = *(const int4*)g;
#endif
}

// ---- fused prep: blocks 0-127 pack Bp; 128-383 e2; 384 zeros loss ---------
// Bp slot s: l=s&63, ks=(s>>6)&7, ni=(s>>9)&3, p=s>>11   (16 passes x 64 codes)
// code n = p*64 + ni*16 + (l&15); c0 = ks*32 + (l>>4)*8; 4 dw = 8 consecutive c
__global__ __launch_bounds__(256) void k_prep(const float* __restrict__ emb,
                                              float* __restrict__ e2,
                                              unsigned* __restrict__ Bp,
                                              float* __restrict__ lossp) {
  const int blk = blockIdx.x, t = threadIdx.x;
  if (blk < 128) {
    const int s = blk * 256 + t;
    const int l = s & 63, ks = (s >> 6) & 7, ni = (s >> 9) & 3, p = s >> 11;
    const int n = (p << 6) + (ni << 4) + (l & 15);
    const int c0 = (ks << 5) + ((l >> 4) << 3);
    const float* er = emb + (size_t)n * C_DIM + c0;
    u32x4 out;
#pragma unroll
    for (int d = 0; d < 4; ++d) {
      __half2 h = __floats2half2_rn(er[2 * d], er[2 * d + 1]);
      out[d] = *(unsigned*)&h;
    }
    *(u32x4*)(Bp + (size_t)s * 4) = out;
  } else if (blk < 384) {
    const int w = t >> 6, l = t & 63;
    const int k = (blk - 128) * 4 + w;
    const float4 v = *(const float4*)(emb + (size_t)k * C_DIM + l * 4);
    float s = v.x * v.x + v.y * v.y + v.z * v.z + v.w * v.w;
    for (int m = 32; m; m >>= 1) s += __shfl_down(s, m, 64);
    if (l == 0) e2[k] = s;
  } else if (t == 0) {
    *lossp = 0.f;
  }
}

// ---- fused main: GEMM+argmin+recheck+gather+store+loss, 512 blocks x 128 px
__global__ __launch_bounds__(256, 2) void k_main(
    const float* __restrict__ x, const unsigned* __restrict__ Bp,
    const float* __restrict__ e2g, const float* __restrict__ emb,
    float* __restrict__ out, float* __restrict__ lossp) {
  __shared__ unsigned Bs[2][8192];    // 2 x 32 KB double buffer
  __shared__ float e2s[K_CODES];      // 4 KB exact fp32 (reused by recheck)
  __shared__ int   bidx_s[128];
  __shared__ int   flist[128];
  __shared__ int   fcnt;
  __shared__ float xs[C_DIM];
  __shared__ float rd[4];
  __shared__ int   ri[4];
  __shared__ float lred[4];

  const int t = threadIdx.x;
  const int wv = t >> 6, l = t & 63;
  const int l15 = l & 15, l4 = l >> 4;
  const int blk = blockIdx.x;         // 512 = 16 b * 32 stripes
  const int b = blk >> 5;
  const int p0 = (blk & 31) << 7;     // 128-px stripe
  const int pxw = p0 + (wv << 5);     // wave's 32-px base
  const float* xb = x + ((size_t)b << 20);

  if (t == 0) fcnt = 0;
#pragma unroll
  for (int i = 0; i < 4; ++i) e2s[t + 256 * i] = e2g[t + 256 * i];

  // stage pass 0 into buf 0: 8 gld16/wave, wave-uniform LDS base
#pragma unroll
  for (int i = 0; i < 8; ++i) {
    const int tile = (wv << 3) + i;              // ni*8+ks in [0,32)
    gld16(Bp + (tile << 8) + (l << 2), (void*)&Bs[0][tile << 8]);
  }

  // A fragments: 2 mi x 8 ks, converted once, register-resident (64 VGPR)
  u32x4 afu[2][8];
#pragma unroll
  for (int mi = 0; mi < 2; ++mi) {
    const int px = pxw + (mi << 4) + l15;
#pragma unroll
    for (int ks = 0; ks < 8; ++ks) {
#pragma unroll
      for (int d = 0; d < 4; ++d) {
        const int c = (ks << 5) + (l4 << 3) + (d << 1);
        const float v0 = xb[((size_t)c << 12) + px];
        const float v1 = xb[((size_t)(c + 1) << 12) + px];
        __half2 h = __floats2half2_rn(v0, v1);
        afu[mi][ks][d] = *(unsigned*)&h;
      }
    }
  }
  __syncthreads();    // e2s + buf0 staged

  float d1[2][4], d2v[2][4];
  int   i1[2][4];
#pragma unroll
  for (int mi = 0; mi < 2; ++mi)
#pragma unroll
    for (int r = 0; r < 4; ++r) { d1[mi][r] = 1e30f; d2v[mi][r] = 1e30f; i1[mi][r] = 0; }

  for (int p = 0; p < 16; ++p) {      // 16 passes x 64 codes
    const int cur = p & 1;
    if (p < 15) {                      // prefetch next pass into other buffer
      const unsigned* src = Bp + ((size_t)(p + 1) << 13);
#pragma unroll
      for (int i = 0; i < 8; ++i) {
        const int tile = (wv << 3) + i;
        gld16(src + (tile << 8) + (l << 2), (void*)&Bs[cur ^ 1][tile << 8]);
      }
    }

    f32x4 acc[2][4];
#pragma unroll
    for (int mi = 0; mi < 2; ++mi)
#pragma unroll
      for (int ni = 0; ni < 4; ++ni) acc[mi][ni] = (f32x4){0.f, 0.f, 0.f, 0.f};

#pragma unroll
    for (int ks = 0; ks < 8; ++ks) {
      const f16x8 a0 = __builtin_bit_cast(f16x8, afu[0][ks]);
      const f16x8 a1 = __builtin_bit_cast(f16x8, afu[1][ks]);
#pragma unroll
      for (int ni = 0; ni < 4; ++ni) {
        const f16x8 bf = __builtin_bit_cast(
            f16x8, *(const u32x4*)&Bs[cur][(((ni << 3) + ks) << 8) + (l << 2)]);
        acc[0][ni] = __builtin_amdgcn_mfma_f32_16x16x32_f16(a0, bf, acc[0][ni], 0, 0, 0);
        acc[1][ni] = __builtin_amdgcn_mfma_f32_16x16x32_f16(a1, bf, acc[1][ni], 0, 0, 0);
      }
    }

    // per-lane top-2 update (pure VALU; merge deferred to end)
    const int pbase = p << 6;
#pragma unroll
    for (int ni = 0; ni < 4; ++ni) {
      const int   c   = pbase + (ni << 4) + l15;
      const float e2v = e2s[c];
#pragma unroll
      for (int mi = 0; mi < 2; ++mi)
#pragma unroll
        for (int r = 0; r < 4; ++r) {
          const float s = fmaf(-2.f, acc[mi][ni][r], e2v);
          const bool lt = s < d1[mi][r];
          d2v[mi][r] = lt ? d1[mi][r] : (s < d2v[mi][r] ? s : d2v[mi][r]);
          i1[mi][r]  = lt ? c : i1[mi][r];
          d1[mi][r]  = lt ? s : d1[mi][r];
        }
    }
    __syncthreads();   // all waves done with Bs[cur]; prefetch drained
  }

  // single cross-lane merge (xor masks flip l15 — 16 lanes share a pixel row)
#pragma unroll
  for (int mi = 0; mi < 2; ++mi) {
#pragma unroll
    for (int r = 0; r < 4; ++r) {
      float pd1 = d1[mi][r], pd2 = d2v[mi][r];
      int   pi1 = i1[mi][r];
#pragma unroll
      for (int m = 1; m < 16; m <<= 1) {
        const float od1 = __shfl_xor(pd1, m);
        const float od2 = __shfl_xor(pd2, m);
        const int   oi1 = __shfl_xor(pi1, m);
        const bool take = (od1 < pd1) || (od1 == pd1 && oi1 < pi1);
        const float loser = take ? pd1 : od1;
        pd2 = fminf(fminf(pd2, od2), loser);
        pd1 = take ? od1 : pd1;
        pi1 = take ? oi1 : pi1;
      }
      if (l15 == 0) {
        const int px = pxw + (mi << 4) + (l4 << 2) + r;    // in-image pixel
        bidx_s[px - p0] = pi1;
        if (pd2 - pd1 < TAU) flist[atomicAdd(&fcnt, 1)] = px;
      }
    }
  }
  __syncthreads();

  // ---- in-block exact fp32 recheck of flagged pixels (r5-validated) -------
  const int n = fcnt;
  for (int ii = 0; ii < n; ++ii) {
    const int px = flist[ii];
    xs[t] = xb[((size_t)t << 12) + px];      // exact x[:,px]
    __syncthreads();
    const float* er = emb + (size_t)(t * 4) * C_DIM;
    float s0 = 0.f, s1 = 0.f, s2 = 0.f, s3 = 0.f;
    for (int c = 0; c < C_DIM; c += 4) {
      const float4 xv = *(const float4*)&xs[c];
      const float4 q0 = *(const float4*)(er + c);
      const float4 q1 = *(const float4*)(er + C_DIM + c);
      const float4 q2 = *(const float4*)(er + 2 * C_DIM + c);
      const float4 q3 = *(const float4*)(er + 3 * C_DIM + c);
      s0 = fmaf(q0.x, xv.x, s0); s0 = fmaf(q0.y, xv.y, s0);
      s0 = fmaf(q0.z, xv.z, s0); s0 = fmaf(q0.w, xv.w, s0);
      s1 = fmaf(q1.x, xv.x, s1); s1 = fmaf(q1.y, xv.y, s1);
      s1 = fmaf(q1.z, xv.z, s1); s1 = fmaf(q1.w, xv.w, s1);
      s2 = fmaf(q2.x, xv.x, s2); s2 = fmaf(q2.y, xv.y, s2);
      s2 = fmaf(q2.z, xv.z, s2); s2 = fmaf(q2.w, xv.w, s2);
      s3 = fmaf(q3.x, xv.x, s3); s3 = fmaf(q3.y, xv.y, s3);
      s3 = fmaf(q3.z, xv.z, s3); s3 = fmaf(q3.w, xv.w, s3);
    }
    float bd = e2s[4 * t] - 2.f * s0;
    int   bk = 4 * t;
    float dv;
    dv = e2s[4 * t + 1] - 2.f * s1; if (dv < bd) { bd = dv; bk = 4 * t + 1; }
    dv = e2s[4 * t + 2] - 2.f * s2; if (dv < bd) { bd = dv; bk = 4 * t + 2; }
    dv = e2s[4 * t + 3] - 2.f * s3; if (dv < bd) { bd = dv; bk = 4 * t + 3; }
#pragma unroll
    for (int m = 1; m < 64; m <<= 1) {
      const float od = __shfl_xor(bd, m);
      const int   oi = __shfl_xor(bk, m);
      if (od < bd || (od == bd && oi < bk)) { bd = od; bk = oi; }
    }
    if (l == 0) { rd[wv] = bd; ri[wv] = bk; }
    __syncthreads();
    if (t == 0) {
      for (int w2 = 1; w2 < 4; ++w2)
        if (rd[w2] < bd || (rd[w2] == bd && ri[w2] < bk)) { bd = rd[w2]; bk = ri[w2]; }
      bidx_s[px - p0] = bk;
    }
    __syncthreads();
  }

  // ---- fused epilogue: gather + transposed store + loss (r1-validated) ----
  float lsum = 0.f;
  const float* xbp = xb + p0;
  float* outb = out + ((size_t)b << 20) + p0;
#pragma unroll 4
  for (int i = 0; i < 32; ++i) {
    const int fidx = t + (i << 8);               // 0..8191 float4 slots
    const int c = fidx >> 5, p4 = (fidx & 31) << 2;
    const float4 x4 = *(const float4*)&xbp[((size_t)c << 12) + p4];
    const int j0 = bidx_s[p4], j1 = bidx_s[p4 + 1];
    const int j2 = bidx_s[p4 + 2], j3 = bidx_s[p4 + 3];
    const float q0 = emb[(size_t)j0 * C_DIM + c];
    const float q1 = emb[(size_t)j1 * C_DIM + c];
    const float q2 = emb[(size_t)j2 * C_DIM + c];
    const float q3 = emb[(size_t)j3 * C_DIM + c];
    const float e0 = q0 - x4.x, e1 = q1 - x4.y, e2d = q2 - x4.z, e3 = q3 - x4.w;
    lsum += e0 * e0 + e1 * e1 + e2d * e2d + e3 * e3;
    float4 o; o.x = q0; o.y = q1; o.z = q2; o.w = q3;
    *(float4*)&outb[((size_t)c << 12) + p4] = o;
  }
  for (int off = 32; off > 0; off >>= 1) lsum += __shfl_down(lsum, off, 64);
  if (l == 0) lred[wv] = lsum;
  __syncthreads();
  if (t == 0) atomicAdd(lossp, lred[0] + lred[1] + lred[2] + lred[3]);
}

__global__ void k_final(const float* __restrict__ ws, float* __restrict__ out) {
  out[N_OUT] = 2.0f * ws[0] / (float)N_OUT;
}

// ================= round-1 fp32 fallback (tiny ws) ==========================
__global__ void k_zero(float* ws) { ws[0] = 0.f; }

__global__ __launch_bounds__(256) void k_e2f(const float* __restrict__ emb,
                                             float* __restrict__ e2) {
  int k = blockIdx.x * 256 + threadIdx.x;
  const float* e = emb + (size_t)k * C_DIM;
  float s = 0.f;
#pragma unroll 8
  for (int c = 0; c < C_DIM; ++c) s += e[c] * e[c];
  e2[k] = s;
}

__global__ __launch_bounds__(256, 4) void k_main_r1(
    const float* __restrict__ x, const float* __restrict__ emb,
    const float* __restrict__ e2, float* __restrict__ out,
    float* __restrict__ loss_acc) {
  __shared__ float smem[64 * 64 + 64 * 64];
  float* xs = smem;
  float* es = smem + 64 * 64;
  float* red_d = smem;
  int* red_i = (int*)(smem + 64 * 16);
  int* bidx_s = (int*)(smem + 64 * 32);
  float* lred = smem + 64 * 32 + 64;
  const int t = threadIdx.x;
  const int tile = blockIdx.x;
  const int b = tile >> 6;
  const int p0 = (tile & 63) << 6;
  const float* xb = x + (size_t)b * C_DIM * HW + p0;
  const int pg = t & 15, kg = t >> 4;
  float best0 = 1e30f, best1 = 1e30f, best2 = 1e30f, best3 = 1e30f;
  int bi0 = 0, bi1 = 0, bi2 = 0, bi3 = 0;
  for (int kc = 0; kc < 16; ++kc) {
    const int k0 = kc * 64;
    float a00 = 0, a01 = 0, a02 = 0, a03 = 0, a10 = 0, a11 = 0, a12 = 0, a13 = 0;
    float a20 = 0, a21 = 0, a22 = 0, a23 = 0, a30 = 0, a31 = 0, a32 = 0, a33 = 0;
    for (int cs0 = 0; cs0 < 4; ++cs0) {
      __syncthreads();
#pragma unroll
      for (int i = 0; i < 4; ++i) {
        int fidx = t + 256 * i;
        int cs = fidx >> 4, p4 = (fidx & 15) << 2;
        *(float4*)&xs[cs * 64 + p4] = *(const float4*)&xb[(size_t)(cs0 * 64 + cs) * HW + p4];
      }
      for (int i = 0; i < 16; ++i) {
        int idx2 = t + 256 * i;
        int cs = idx2 >> 6, kk = idx2 & 63;
        es[cs * 64 + kk] = emb[(size_t)(k0 + kk) * C_DIM + cs0 * 64 + cs];
      }
      __syncthreads();
#pragma unroll 8
      for (int cs = 0; cs < 64; ++cs) {
        const float4 xv = *(const float4*)&xs[cs * 64 + (pg << 2)];
        const float4 ev = *(const float4*)&es[cs * 64 + (kg << 2)];
        a00 += xv.x * ev.x; a01 += xv.x * ev.y; a02 += xv.x * ev.z; a03 += xv.x * ev.w;
        a10 += xv.y * ev.x; a11 += xv.y * ev.y; a12 += xv.y * ev.z; a13 += xv.y * ev.w;
        a20 += xv.z * ev.x; a21 += xv.z * ev.y; a22 += xv.z * ev.z; a23 += xv.z * ev.w;
        a30 += xv.w * ev.x; a31 += xv.w * ev.y; a32 += xv.w * ev.z; a33 += xv.w * ev.w;
      }
    }
    const int kb = k0 + (kg << 2);
    const float e20 = e2[kb], e21 = e2[kb + 1], e22 = e2[kb + 2], e23 = e2[kb + 3];
    float s;
    s = e20 - 2.f * a00; if (s < best0) { best0 = s; bi0 = kb; }
    s = e21 - 2.f * a01; if (s < best0) { best0 = s; bi0 = kb + 1; }
    s = e22 - 2.f * a02; if (s < best0) { best0 = s; bi0 = kb + 2; }
    s = e23 - 2.f * a03; if (s < best0) { best0 = s; bi0 = kb + 3; }
    s = e20 - 2.f * a10; if (s < best1) { best1 = s; bi1 = kb; }
    s = e21 - 2.f * a11; if (s < best1) { best1 = s; bi1 = kb + 1; }
    s = e22 - 2.f * a12; if (s < best1) { best1 = s; bi1 = kb + 2; }
    s = e23 - 2.f * a13; if (s < best1) { best1 = s; bi1 = kb + 3; }
    s = e20 - 2.f * a20; if (s < best2) { best2 = s; bi2 = kb; }
    s = e21 - 2.f * a21; if (s < best2) { best2 = s; bi2 = kb + 1; }
    s = e22 - 2.f * a22; if (s < best2) { best2 = s; bi2 = kb + 2; }
    s = e23 - 2.f * a23; if (s < best2) { best2 = s; bi2 = kb + 3; }
    s = e20 - 2.f * a30; if (s < best3) { best3 = s; bi3 = kb; }
    s = e21 - 2.f * a31; if (s < best3) { best3 = s; bi3 = kb + 1; }
    s = e22 - 2.f * a32; if (s < best3) { best3 = s; bi3 = kb + 2; }
    s = e23 - 2.f * a33; if (s < best3) { best3 = s; bi3 = kb + 3; }
  }
  __syncthreads();
  const int prow = pg << 2;
  red_d[(prow + 0) * 16 + kg] = best0; red_i[(prow + 0) * 16 + kg] = bi0;
  red_d[(prow + 1) * 16 + kg] = best1; red_i[(prow + 1) * 16 + kg] = bi1;
  red_d[(prow + 2) * 16 + kg] = best2; red_i[(prow + 2) * 16 + kg] = bi2;
  red_d[(prow + 3) * 16 + kg] = best3; red_i[(prow + 3) * 16 + kg] = bi3;
  __syncthreads();
  if (t < 64) {
    float bd = red_d[t * 16];
    int bk = red_i[t * 16];
    for (int g = 1; g < 16; ++g) {
      float d = red_d[t * 16 + g];
      int k = red_i[t * 16 + g];
      if (d < bd || (d == bd && k < bk)) { bd = d; bk = k; }
    }
    bidx_s[t] = bk;
  }
  __syncthreads();
  float lsum = 0.f;
  float* outb = out + (size_t)b * C_DIM * HW + p0;
#pragma unroll 4
  for (int i = 0; i < 16; ++i) {
    int fidx = t + 256 * i;
    int c = fidx >> 4, p4 = (fidx & 15) << 2;
    const float4 x4 = *(const float4*)&xb[(size_t)c * HW + p4];
    const int j0 = bidx_s[p4], j1 = bidx_s[p4 + 1], j2 = bidx_s[p4 + 2], j3 = bidx_s[p4 + 3];
    const float q0 = emb[(size_t)j0 * C_DIM + c];
    const float q1 = emb[(size_t)j1 * C_DIM + c];
    const float q2 = emb[(size_t)j2 * C_DIM + c];
    const float q3 = emb[(size_t)j3 * C_DIM + c];
    const float d0 = q0 - x4.x, d1 = q1 - x4.y, d2 = q2 - x4.z, d3 = q3 - x4.w;
    lsum += d0 * d0 + d1 * d1 + d2 * d2 + d3 * d3;
    float4 o; o.x = q0; o.y = q1; o.z = q2; o.w = q3;
    *(float4*)&outb[(size_t)c * HW + p4] = o;
  }
  for (int off = 32; off > 0; off >>= 1) lsum += __shfl_down(lsum, off, 64);
  if ((t & 63) == 0) lred[t >> 6] = lsum;
  __syncthreads();
  if (t == 0) atomicAdd(loss_acc, lred[0] + lred[1] + lred[2] + lred[3]);
}

// ============================================================================
extern "C" void kernel_launch(void* const* d_in, const int* in_sizes, int n_in,
                              void* d_out, int out_size, void* d_ws, size_t ws_size,
                              hipStream_t stream) {
  const float* x = (const float*)d_in[0];
  const float* emb = (const float*)d_in[1];
  float* out = (float*)d_out;
  char* ws = (char*)d_ws;

  // ws: 0 loss | 256 e2 (4 KB) | 8192 Bp (512 KB) | end 532480
  const size_t NEED = 532480;
  if (ws_size >= NEED) {
    float* lossp = (float*)ws;
    float* e2 = (float*)(ws + 256);
    unsigned* Bp = (unsigned*)(ws + 8192);
    k_prep<<<385, 256, 0, stream>>>(emb, e2, Bp, lossp);
    k_main<<<512, 256, 0, stream>>>(x, Bp, e2, emb, out, lossp);
    k_final<<<1, 1, 0, stream>>>(lossp, out);
  } else {
    float* wsf = (float*)ws;
    float* e2 = wsf + 64;
    k_zero<<<1, 1, 0, stream>>>(wsf);
    k_e2f<<<K_CODES / 256, 256, 0, stream>>>(emb, e2);
    k_main_r1<<<1024, 256, 0, stream>>>(x, emb, e2, out, wsf);
    k_final<<<1, 1, 0, stream>>>(wsf, out);
  }
}

// Round 7
// 257.836 us; speedup vs baseline: 2.4313x; 2.2732x over previous
//
#include <hip/hip_runtime.h>
#include <hip/hip_fp16.h>

// VectorQuantizer — round 7: consolidation to measured-good r3 pipeline shape
// (separate, individually-profiled kernels) with ONE hot-loop change:
// k_main = r3's exact GEMM structure (single 64KB B buffer, stage->barrier->
// compute->barrier, 8 passes x 128 codes) + register-only top-2 with a single
// end merge (replaces r3's per-pass shfl/LDS merges; merge code itself
// validated inside r4's kernel). Flags -> global list (parallel r3 recheck).
// 5 dispatches: k_prep, k_main, k_recheck, k_epi, k_final.
//
// score[k] = ||e_k||^2 - 2*dot(fp16(x),fp16(e_k))  [fp32 MFMA accum]
// near-ties (gap < TAU) exact-fp32 rechecked.

#define C_DIM   256
#define K_CODES 1024
#define HW      4096
#define N_OUT   (16 * C_DIM * HW)
#define TAU     0.25f
#define LISTCAP 65536
#define RPP     8
#define RGRID   512

typedef _Float16 f16x8 __attribute__((ext_vector_type(8)));
typedef float    f32x4 __attribute__((ext_vector_type(4)));
typedef unsigned u32x4 __attribute__((ext_vector_type(4)));

__device__ __forceinline__ void gld16(const void* g, void* lds) {
#if __has_builtin(__builtin_amdgcn_global_load_lds)
  __builtin_amdgcn_global_load_lds(
      (const __attribute__((address_space(1))) unsigned int*)g,
      (__attribute__((address_space(3))) unsigned int*)lds, 16, 0, 0);
#else
  ((int4*)lds)[threadIdx.x & 63] = *(const int4*)g;
#endif
}

// ---- fused prep: blocks 0-127 pack Bp; 128-383 e2; 384 zeros loss+cnt -----
// Bp slot s: l=s&63, ks=(s>>6)&7, ni=(s>>9)&7, cb=s>>12  (8 passes x 128 codes)
// code n = cb*128 + ni*16 + (l&15); c0 = ks*32 + (l>>4)*8; 4 dw = 8 consec. c
__global__ __launch_bounds__(256) void k_prep(const float* __restrict__ emb,
                                              float* __restrict__ e2,
                                              unsigned* __restrict__ Bp,
                                              float* __restrict__ lossp,
                                              int* __restrict__ cntp) {
  const int blk = blockIdx.x, t = threadIdx.x;
  if (blk < 128) {
    const int s = blk * 256 + t;
    const int l = s & 63, ks = (s >> 6) & 7, ni = (s >> 9) & 7, cb = s >> 12;
    const int n = (cb << 7) + (ni << 4) + (l & 15);
    const int c0 = (ks << 5) + ((l >> 4) << 3);
    const float* er = emb + (size_t)n * C_DIM + c0;
    u32x4 out;
#pragma unroll
    for (int d = 0; d < 4; ++d) {
      __half2 h = __floats2half2_rn(er[2 * d], er[2 * d + 1]);
      out[d] = *(unsigned*)&h;
    }
    *(u32x4*)(Bp + (size_t)s * 4) = out;
  } else if (blk < 384) {
    const int w = t >> 6, l = t & 63;
    const int k = (blk - 128) * 4 + w;
    const float4 v = *(const float4*)(emb + (size_t)k * C_DIM + l * 4);
    float s = v.x * v.x + v.y * v.y + v.z * v.z + v.w * v.w;
    for (int m = 32; m; m >>= 1) s += __shfl_down(s, m, 64);
    if (l == 0) e2[k] = s;
  } else if (t == 0) {
    *lossp = 0.f; *cntp = 0;
  }
}

// ---- main: r3 GEMM structure + register top-2 / single end merge ----------
__global__ __launch_bounds__(256, 2) void k_main(
    const float* __restrict__ x, const unsigned* __restrict__ Bp,
    const float* __restrict__ e2g, int* __restrict__ idxw,
    int* __restrict__ list, int* __restrict__ cntp) {
  __shared__ unsigned Bs[64 * 256];   // 64 KB single buffer: [tile=ni*8+ks][lane dw]
  __shared__ float e2s[K_CODES];      // 4 KB

  const int t = threadIdx.x;
  const int wv = t >> 6, l = t & 63;
  const int l15 = l & 15, l4 = l >> 4;
  const int blk = blockIdx.x;         // 512 = 16 b * 32 stripes
  const int b = blk >> 5;
  const int p0 = (blk & 31) << 7;     // 128-px stripe
  const int pxw = p0 + (wv << 5);     // wave's 32-px base
  const float* xb = x + ((size_t)b << 20);

#pragma unroll
  for (int i = 0; i < 4; ++i) e2s[t + 256 * i] = e2g[t + 256 * i];

  // A fragments: 2 mi x 8 ks, converted once, register-resident
  u32x4 afu[2][8];
#pragma unroll
  for (int mi = 0; mi < 2; ++mi) {
    const int px = pxw + (mi << 4) + l15;
#pragma unroll
    for (int ks = 0; ks < 8; ++ks) {
#pragma unroll
      for (int d = 0; d < 4; ++d) {
        const int c = (ks << 5) + (l4 << 3) + (d << 1);
        const float v0 = xb[((size_t)c << 12) + px];
        const float v1 = xb[((size_t)(c + 1) << 12) + px];
        __half2 h = __floats2half2_rn(v0, v1);
        afu[mi][ks][d] = *(unsigned*)&h;
      }
    }
  }

  float d1[2][4], d2v[2][4];
  int   i1[2][4];
#pragma unroll
  for (int mi = 0; mi < 2; ++mi)
#pragma unroll
    for (int r = 0; r < 4; ++r) { d1[mi][r] = 1e30f; d2v[mi][r] = 1e30f; i1[mi][r] = 0; }

  for (int cb = 0; cb < 8; ++cb) {
    __syncthreads();                            // prev-pass consumers done
    const unsigned* src0 = Bp + ((size_t)cb << 14);
#pragma unroll
    for (int i = 0; i < 16; ++i) {
      const int tile = (wv << 4) + i;           // ni*8+ks in [0,64)
      gld16(src0 + (tile << 8) + (l << 2), (void*)&Bs[tile << 8]);
    }
    __syncthreads();                            // staged data visible

    f32x4 acc[2][8];
#pragma unroll
    for (int mi = 0; mi < 2; ++mi)
#pragma unroll
      for (int ni = 0; ni < 8; ++ni) acc[mi][ni] = (f32x4){0.f, 0.f, 0.f, 0.f};

#pragma unroll
    for (int ks = 0; ks < 8; ++ks) {
      const f16x8 a0 = __builtin_bit_cast(f16x8, afu[0][ks]);
      const f16x8 a1 = __builtin_bit_cast(f16x8, afu[1][ks]);
#pragma unroll
      for (int ni = 0; ni < 8; ++ni) {
        const f16x8 bf = __builtin_bit_cast(
            f16x8, *(const u32x4*)&Bs[(((ni << 3) + ks) << 8) + (l << 2)]);
        acc[0][ni] = __builtin_amdgcn_mfma_f32_16x16x32_f16(a0, bf, acc[0][ni], 0, 0, 0);
        acc[1][ni] = __builtin_amdgcn_mfma_f32_16x16x32_f16(a1, bf, acc[1][ni], 0, 0, 0);
      }
    }

    // register top-2 update (pure VALU; merge deferred to kernel end)
    const int cb128 = cb << 7;
#pragma unroll
    for (int ni = 0; ni < 8; ++ni) {
      const int   c   = cb128 + (ni << 4) + l15;
      const float e2v = e2s[c];
#pragma unroll
      for (int mi = 0; mi < 2; ++mi)
#pragma unroll
        for (int r = 0; r < 4; ++r) {
          const float s = fmaf(-2.f, acc[mi][ni][r], e2v);
          const bool lt = s < d1[mi][r];
          d2v[mi][r] = lt ? d1[mi][r] : (s < d2v[mi][r] ? s : d2v[mi][r]);
          i1[mi][r]  = lt ? c : i1[mi][r];
          d1[mi][r]  = lt ? s : d1[mi][r];
        }
    }
  }

  // single cross-lane merge (xor masks flip l15 — 16 lanes share a pixel row)
#pragma unroll
  for (int mi = 0; mi < 2; ++mi) {
#pragma unroll
    for (int r = 0; r < 4; ++r) {
      float pd1 = d1[mi][r], pd2 = d2v[mi][r];
      int   pi1 = i1[mi][r];
#pragma unroll
      for (int m = 1; m < 16; m <<= 1) {
        const float od1 = __shfl_xor(pd1, m);
        const float od2 = __shfl_xor(pd2, m);
        const int   oi1 = __shfl_xor(pi1, m);
        const bool take = (od1 < pd1) || (od1 == pd1 && oi1 < pi1);
        const float loser = take ? pd1 : od1;
        pd2 = fminf(fminf(pd2, od2), loser);
        pd1 = take ? od1 : pd1;
        pi1 = take ? oi1 : pi1;
      }
      if (l15 == 0) {
        const int px = pxw + (mi << 4) + (l4 << 2) + r;
        const int gp = (b << 12) + px;
        idxw[gp] = pi1;
        if (pd2 - pd1 < TAU) {
          const int pos = atomicAdd(cntp, 1);
          if (pos < LISTCAP) list[pos] = gp;
        }
      }
    }
  }
}

// ---- exact fp32 recheck: 8 flagged pixels per block share codebook sweep --
__global__ __launch_bounds__(256) void k_recheck(
    const float* __restrict__ x, const float* __restrict__ emb,
    const float* __restrict__ e2, const int* __restrict__ list,
    const int* __restrict__ cntp, int* __restrict__ idxw) {
  __shared__ float xs[RPP][C_DIM];
  __shared__ int   gps[RPP];
  __shared__ float wbest[RPP][4];
  __shared__ int   wbidx[RPP][4];
  const int t = threadIdx.x;
  const int cnt = min(*cntp, LISTCAP);
  float e2l[4];
#pragma unroll
  for (int j = 0; j < 4; ++j) e2l[j] = e2[t * 4 + j];

  for (int base = blockIdx.x * RPP; base < cnt; base += RGRID * RPP) {
    __syncthreads();
    if (t < RPP) gps[t] = (base + t < cnt) ? list[base + t] : -1;
    __syncthreads();
#pragma unroll
    for (int s = 0; s < RPP; ++s) {
      const int gp = gps[s];
      if (gp >= 0)
        xs[s][t] = x[((size_t)(gp >> 12) << 20) + ((size_t)t << 12) + (gp & 4095)];
    }
    __syncthreads();

    float acc[4][RPP];
#pragma unroll
    for (int j = 0; j < 4; ++j)
#pragma unroll
      for (int s = 0; s < RPP; ++s) acc[j][s] = 0.f;

    const float* er = emb + (size_t)(t * 4) * C_DIM;
    for (int c = 0; c < C_DIM; c += 4) {
      const float4 e0 = *(const float4*)(er + c);
      const float4 e1 = *(const float4*)(er + C_DIM + c);
      const float4 e2r = *(const float4*)(er + 2 * C_DIM + c);
      const float4 e3 = *(const float4*)(er + 3 * C_DIM + c);
#pragma unroll
      for (int s = 0; s < RPP; ++s) {
        const float4 xv = *(const float4*)&xs[s][c];
        acc[0][s] = fmaf(e0.x, xv.x, acc[0][s]); acc[0][s] = fmaf(e0.y, xv.y, acc[0][s]);
        acc[0][s] = fmaf(e0.z, xv.z, acc[0][s]); acc[0][s] = fmaf(e0.w, xv.w, acc[0][s]);
        acc[1][s] = fmaf(e1.x, xv.x, acc[1][s]); acc[1][s] = fmaf(e1.y, xv.y, acc[1][s]);
        acc[1][s] = fmaf(e1.z, xv.z, acc[1][s]); acc[1][s] = fmaf(e1.w, xv.w, acc[1][s]);
        acc[2][s] = fmaf(e2r.x, xv.x, acc[2][s]); acc[2][s] = fmaf(e2r.y, xv.y, acc[2][s]);
        acc[2][s] = fmaf(e2r.z, xv.z, acc[2][s]); acc[2][s] = fmaf(e2r.w, xv.w, acc[2][s]);
        acc[3][s] = fmaf(e3.x, xv.x, acc[3][s]); acc[3][s] = fmaf(e3.y, xv.y, acc[3][s]);
        acc[3][s] = fmaf(e3.z, xv.z, acc[3][s]); acc[3][s] = fmaf(e3.w, xv.w, acc[3][s]);
      }
    }

    for (int s = 0; s < RPP; ++s) {
      float bd = 1e30f;
      int   bk = 0;
#pragma unroll
      for (int j = 0; j < 4; ++j) {
        const float sc = fmaf(-2.f, acc[j][s], e2l[j]);
        if (sc < bd) { bd = sc; bk = t * 4 + j; }   // ascending j => first idx
      }
#pragma unroll
      for (int m = 1; m < 64; m <<= 1) {
        const float od = __shfl_xor(bd, m);
        const int   oi = __shfl_xor(bk, m);
        if (od < bd || (od == bd && oi < bk)) { bd = od; bk = oi; }
      }
      if ((t & 63) == 0) { wbest[s][t >> 6] = bd; wbidx[s][t >> 6] = bk; }
    }
    __syncthreads();
    if (t < RPP && gps[t] >= 0) {
      float bd = wbest[t][0];
      int   bk = wbidx[t][0];
      for (int wv = 1; wv < 4; ++wv)
        if (wbest[t][wv] < bd || (wbest[t][wv] == bd && wbidx[t][wv] < bk)) {
          bd = wbest[t][wv]; bk = wbidx[t][wv];
        }
      idxw[gps[t]] = bk;
    }
  }
}

// ---- epilogue: gather + transposed store + loss (r1/r3-validated) ---------
__global__ __launch_bounds__(256) void k_epi(const float* __restrict__ x,
                                             const float* __restrict__ emb,
                                             const int* __restrict__ idxw,
                                             float* __restrict__ out,
                                             float* __restrict__ loss_acc) {
  __shared__ int bidx_s[64];
  __shared__ float lred[4];
  const int t = threadIdx.x;
  const int tile = blockIdx.x;     // 1024 = 16 b * 64
  const int b = tile >> 6, p0 = (tile & 63) << 6;
  const float* xb = x + ((size_t)b << 20) + p0;
  float* outb = out + ((size_t)b << 20) + p0;
  if (t < 64) bidx_s[t] = idxw[((size_t)b << 12) + p0 + t] & 1023;
  __syncthreads();
  float lsum = 0.f;
#pragma unroll 4
  for (int i = 0; i < 16; ++i) {
    const int fidx = t + 256 * i;
    const int c = fidx >> 4, p4 = (fidx & 15) << 2;
    const float4 x4 = *(const float4*)&xb[((size_t)c << 12) + p4];
    const int j0 = bidx_s[p4], j1 = bidx_s[p4 + 1], j2 = bidx_s[p4 + 2], j3 = bidx_s[p4 + 3];
    const float q0 = emb[(size_t)j0 * C_DIM + c];
    const float q1 = emb[(size_t)j1 * C_DIM + c];
    const float q2 = emb[(size_t)j2 * C_DIM + c];
    const float q3 = emb[(size_t)j3 * C_DIM + c];
    const float d0 = q0 - x4.x, dd1 = q1 - x4.y, dd2 = q2 - x4.z, dd3 = q3 - x4.w;
    lsum += d0 * d0 + dd1 * dd1 + dd2 * dd2 + dd3 * dd3;
    float4 o; o.x = q0; o.y = q1; o.z = q2; o.w = q3;
    *(float4*)&outb[((size_t)c << 12) + p4] = o;
  }
  for (int off = 32; off > 0; off >>= 1) lsum += __shfl_down(lsum, off, 64);
  if ((t & 63) == 0) lred[t >> 6] = lsum;
  __syncthreads();
  if (t == 0) atomicAdd(loss_acc, lred[0] + lred[1] + lred[2] + lred[3]);
}

__global__ void k_final(const float* __restrict__ ws, float* __restrict__ out) {
  out[N_OUT] = 2.0f * ws[0] / (float)N_OUT;
}

// ================= round-1 fp32 fallback (tiny ws) ==========================
__global__ void k_zero(float* ws) { ws[0] = 0.f; }

__global__ __launch_bounds__(256) void k_e2f(const float* __restrict__ emb,
                                             float* __restrict__ e2) {
  int k = blockIdx.x * 256 + threadIdx.x;
  const float* e = emb + (size_t)k * C_DIM;
  float s = 0.f;
#pragma unroll 8
  for (int c = 0; c < C_DIM; ++c) s += e[c] * e[c];
  e2[k] = s;
}

__global__ __launch_bounds__(256, 4) void k_main_r1(
    const float* __restrict__ x, const float* __restrict__ emb,
    const float* __restrict__ e2, float* __restrict__ out,
    float* __restrict__ loss_acc) {
  __shared__ float smem[64 * 64 + 64 * 64];
  float* xs = smem;
  float* es = smem + 64 * 64;
  float* red_d = smem;
  int* red_i = (int*)(smem + 64 * 16);
  int* bidx_s = (int*)(smem + 64 * 32);
  float* lred = smem + 64 * 32 + 64;
  const int t = threadIdx.x;
  const int tile = blockIdx.x;
  const int b = tile >> 6;
  const int p0 = (tile & 63) << 6;
  const float* xb = x + (size_t)b * C_DIM * HW + p0;
  const int pg = t & 15, kg = t >> 4;
  float best0 = 1e30f, best1 = 1e30f, best2 = 1e30f, best3 = 1e30f;
  int bi0 = 0, bi1 = 0, bi2 = 0, bi3 = 0;
  for (int kc = 0; kc < 16; ++kc) {
    const int k0 = kc * 64;
    float a00 = 0, a01 = 0, a02 = 0, a03 = 0, a10 = 0, a11 = 0, a12 = 0, a13 = 0;
    float a20 = 0, a21 = 0, a22 = 0, a23 = 0, a30 = 0, a31 = 0, a32 = 0, a33 = 0;
    for (int cs0 = 0; cs0 < 4; ++cs0) {
      __syncthreads();
#pragma unroll
      for (int i = 0; i < 4; ++i) {
        int fidx = t + 256 * i;
        int cs = fidx >> 4, p4 = (fidx & 15) << 2;
        *(float4*)&xs[cs * 64 + p4] = *(const float4*)&xb[(size_t)(cs0 * 64 + cs) * HW + p4];
      }
      for (int i = 0; i < 16; ++i) {
        int idx2 = t + 256 * i;
        int cs = idx2 >> 6, kk = idx2 & 63;
        es[cs * 64 + kk] = emb[(size_t)(k0 + kk) * C_DIM + cs0 * 64 + cs];
      }
      __syncthreads();
#pragma unroll 8
      for (int cs = 0; cs < 64; ++cs) {
        const float4 xv = *(const float4*)&xs[cs * 64 + (pg << 2)];
        const float4 ev = *(const float4*)&es[cs * 64 + (kg << 2)];
        a00 += xv.x * ev.x; a01 += xv.x * ev.y; a02 += xv.x * ev.z; a03 += xv.x * ev.w;
        a10 += xv.y * ev.x; a11 += xv.y * ev.y; a12 += xv.y * ev.z; a13 += xv.y * ev.w;
        a20 += xv.z * ev.x; a21 += xv.z * ev.y; a22 += xv.z * ev.z; a23 += xv.z * ev.w;
        a30 += xv.w * ev.x; a31 += xv.w * ev.y; a32 += xv.w * ev.z; a33 += xv.w * ev.w;
      }
    }
    const int kb = k0 + (kg << 2);
    const float e20 = e2[kb], e21 = e2[kb + 1], e22 = e2[kb + 2], e23 = e2[kb + 3];
    float s;
    s = e20 - 2.f * a00; if (s < best0) { best0 = s; bi0 = kb; }
    s = e21 - 2.f * a01; if (s < best0) { best0 = s; bi0 = kb + 1; }
    s = e22 - 2.f * a02; if (s < best0) { best0 = s; bi0 = kb + 2; }
    s = e23 - 2.f * a03; if (s < best0) { best0 = s; bi0 = kb + 3; }
    s = e20 - 2.f * a10; if (s < best1) { best1 = s; bi1 = kb; }
    s = e21 - 2.f * a11; if (s < best1) { best1 = s; bi1 = kb + 1; }
    s = e22 - 2.f * a12; if (s < best1) { best1 = s; bi1 = kb + 2; }
    s = e23 - 2.f * a13; if (s < best1) { best1 = s; bi1 = kb + 3; }
    s = e20 - 2.f * a20; if (s < best2) { best2 = s; bi2 = kb; }
    s = e21 - 2.f * a21; if (s < best2) { best2 = s; bi2 = kb + 1; }
    s = e22 - 2.f * a22; if (s < best2) { best2 = s; bi2 = kb + 2; }
    s = e23 - 2.f * a23; if (s < best2) { best2 = s; bi2 = kb + 3; }
    s = e20 - 2.f * a30; if (s < best3) { best3 = s; bi3 = kb; }
    s = e21 - 2.f * a31; if (s < best3) { best3 = s; bi3 = kb + 1; }
    s = e22 - 2.f * a32; if (s < best3) { best3 = s; bi3 = kb + 2; }
    s = e23 - 2.f * a33; if (s < best3) { best3 = s; bi3 = kb + 3; }
  }
  __syncthreads();
  const int prow = pg << 2;
  red_d[(prow + 0) * 16 + kg] = best0; red_i[(prow + 0) * 16 + kg] = bi0;
  red_d[(prow + 1) * 16 + kg] = best1; red_i[(prow + 1) * 16 + kg] = bi1;
  red_d[(prow + 2) * 16 + kg] = best2; red_i[(prow + 2) * 16 + kg] = bi2;
  red_d[(prow + 3) * 16 + kg] = best3; red_i[(prow + 3) * 16 + kg] = bi3;
  __syncthreads();
  if (t < 64) {
    float bd = red_d[t * 16];
    int bk = red_i[t * 16];
    for (int g = 1; g < 16; ++g) {
      float d = red_d[t * 16 + g];
      int k = red_i[t * 16 + g];
      if (d < bd || (d == bd && k < bk)) { bd = d; bk = k; }
    }
    bidx_s[t] = bk;
  }
  __syncthreads();
  float lsum = 0.f;
  float* outb = out + (size_t)b * C_DIM * HW + p0;
#pragma unroll 4
  for (int i = 0; i < 16; ++i) {
    int fidx = t + 256 * i;
    int c = fidx >> 4, p4 = (fidx & 15) << 2;
    const float4 x4 = *(const float4*)&xb[(size_t)c * HW + p4];
    const int j0 = bidx_s[p4], j1 = bidx_s[p4 + 1], j2 = bidx_s[p4 + 2], j3 = bidx_s[p4 + 3];
    const float q0 = emb[(size_t)j0 * C_DIM + c];
    const float q1 = emb[(size_t)j1 * C_DIM + c];
    const float q2 = emb[(size_t)j2 * C_DIM + c];
    const float q3 = emb[(size_t)j3 * C_DIM + c];
    const float d0 = q0 - x4.x, d1 = q1 - x4.y, d2 = q2 - x4.z, d3 = q3 - x4.w;
    lsum += d0 * d0 + d1 * d1 + d2 * d2 + d3 * d3;
    float4 o; o.x = q0; o.y = q1; o.z = q2; o.w = q3;
    *(float4*)&outb[(size_t)c * HW + p4] = o;
  }
  for (int off = 32; off > 0; off >>= 1) lsum += __shfl_down(lsum, off, 64);
  if ((t & 63) == 0) lred[t >> 6] = lsum;
  __syncthreads();
  if (t == 0) atomicAdd(loss_acc, lred[0] + lred[1] + lred[2] + lred[3]);
}

// ============================================================================
extern "C" void kernel_launch(void* const* d_in, const int* in_sizes, int n_in,
                              void* d_out, int out_size, void* d_ws, size_t ws_size,
                              hipStream_t stream) {
  const float* x = (const float*)d_in[0];
  const float* emb = (const float*)d_in[1];
  float* out = (float*)d_out;
  char* ws = (char*)d_ws;

  // ws: 0 loss | 4 cnt | 256 e2 (4 KB) | 8192 idx (256 KB)
  //     | 270336 list (256 KB) | 532480 Bp (512 KB) | end 1056768
  const size_t NEED = 1056768;
  if (ws_size >= NEED) {
    float* lossp = (float*)ws;
    int* cntp = (int*)(ws + 4);
    float* e2 = (float*)(ws + 256);
    int* idx = (int*)(ws + 8192);
    int* list = (int*)(ws + 270336);
    unsigned* Bp = (unsigned*)(ws + 532480);
    k_prep<<<385, 256, 0, stream>>>(emb, e2, Bp, lossp, cntp);
    k_main<<<512, 256, 0, stream>>>(x, Bp, e2, idx, list, cntp);
    k_recheck<<<RGRID, 256, 0, stream>>>(x, emb, e2, list, cntp, idx);
    k_epi<<<1024, 256, 0, stream>>>(x, emb, idx, out, lossp);
    k_final<<<1, 1, 0, stream>>>(lossp, out);
  } else {
    float* wsf = (float*)ws;
    float* e2 = wsf + 64;
    k_zero<<<1, 1, 0, stream>>>(wsf);
    k_e2f<<<K_CODES / 256, 256, 0, stream>>>(emb, e2);
    k_main_r1<<<1024, 256, 0, stream>>>(x, emb, e2, out, wsf);
    k_final<<<1, 1, 0, stream>>>(wsf, out);
  }
}